// Round 2
// baseline (165.594 us; speedup 1.0000x reference)
//
#include <hip/hip_runtime.h>

#define SCALE_F 173.71779276130078f   // 400 / ln(10)
#define BLOCK 256
#define WPB 4                         // waves per block

// One wave per segment. segment_ids are sorted, so segment g occupies a
// contiguous token range [s0, s1) found by windowed binary search.
// Weights are wave-uniform -> scalar loads (SGPR), no LDS needed.
__global__ __launch_bounds__(BLOCK) void strength_seg_kernel(
    const float* __restrict__ x,    // [N][6]
    const float* __restrict__ W1,   // [6][32]
    const float* __restrict__ b1,   // [32]
    const float* __restrict__ wr,   // [32]
    const float* __restrict__ brp,  // scalar
    const float* __restrict__ wz,   // [32]
    const float* __restrict__ bzp,  // scalar
    const int*   __restrict__ seg,  // [N] sorted
    int N, int G,
    float* __restrict__ out)        // [G]
{
    const int lane = threadIdx.x & 63;
    const int g    = blockIdx.x * WPB + (threadIdx.x >> 6);
    if (g >= G) return;

    // ---- windowed dual binary search ----
    // lower_bound(g) in [loa,hia], lower_bound(g+1) in [lob,hib].
    // Window center = expected start (N*g/G); probes VERIFY the window, so
    // this is correct for any sorted input (worst case falls back to [0,N]).
    int loa = 0, hia = N, lob = 0, hib = N;
    {
        int ca = (int)(((long long)N * g)       / G);
        int cb = (int)(((long long)N * (g + 1)) / G);
        const int W = 8192;
        int wl, wh;
        wl = ca - W; if (wl < 0) wl = 0;
        wh = ca + W; if (wh > N) wh = N;
        if (wl > 0 && seg[wl - 1] < g)  loa = wl;   // answer >= wl
        if (wh < N && seg[wh]     >= g) hia = wh;   // answer <= wh
        wl = cb - W; if (wl < 0) wl = 0;
        wh = cb + W; if (wh > N) wh = N;
        if (wl > 0 && seg[wl - 1] <= g) lob = wl;
        if (wh < N && seg[wh]     >  g) hib = wh;
    }
    // interleaved searches: two independent load chains per iteration
    while ((loa < hia) || (lob < hib)) {
        if (loa < hia) {
            int m = (loa + hia) >> 1;
            int v = seg[m];
            if (v < g) loa = m + 1; else hia = m;
        }
        if (lob < hib) {
            int m = (lob + hib) >> 1;
            int v = seg[m];
            if (v <= g) lob = m + 1; else hib = m;
        }
    }
    const int s0 = loa, s1 = lob;

    const float brv = *brp;
    const float bzv = *bzp;

    // ---- stream the segment, 64 tokens per slice ----
    float E = 0.0f, ER = 0.0f;
    for (int t0 = s0; t0 < s1; t0 += 64) {
        const int  t = t0 + lane;
        const bool v = (t < s1);
        float x0 = 0.f, x1 = 0.f, x2 = 0.f, x3 = 0.f, x4 = 0.f, x5 = 0.f;
        if (v) {
            const float* xp = x + (size_t)t * 6;   // 24B rows, 8B aligned
            float2 a = *reinterpret_cast<const float2*>(xp + 0);
            float2 b = *reinterpret_cast<const float2*>(xp + 2);
            float2 c = *reinterpret_cast<const float2*>(xp + 4);
            x0 = a.x; x1 = a.y; x2 = b.x; x3 = b.y; x4 = c.x; x5 = c.y;
        }
        float r = brv, z = bzv;
        #pragma unroll
        for (int j = 0; j < 32; ++j) {
            // weights are wave-uniform -> compiler emits s_load, SGPR operands
            float h = fmaf(x0, W1[0 * 32 + j],
                      fmaf(x1, W1[1 * 32 + j],
                      fmaf(x2, W1[2 * 32 + j],
                      fmaf(x3, W1[3 * 32 + j],
                      fmaf(x4, W1[4 * 32 + j],
                      fmaf(x5, W1[5 * 32 + j], b1[j]))))));
            h = fmaxf(h, 0.0f);
            r = fmaf(h, wr[j], r);
            z = fmaf(h, wz[j], z);
        }
        if (v) {
            float e = __expf(z);   // no max-shift: |z| small, ratio invariant
            E += e;
            ER = fmaf(e, r, ER);
        }
    }

    // ---- wave reduction ----
    #pragma unroll
    for (int d = 32; d; d >>= 1) {
        E  += __shfl_xor(E,  d);
        ER += __shfl_xor(ER, d);
    }
    if (lane == 0)
        out[g] = (E > 0.0f) ? (SCALE_F * ER / E) : 0.0f;
}

extern "C" void kernel_launch(void* const* d_in, const int* in_sizes, int n_in,
                              void* d_out, int out_size, void* d_ws, size_t ws_size,
                              hipStream_t stream) {
    const float* x   = (const float*)d_in[0];
    const float* W1  = (const float*)d_in[1];
    const float* b1  = (const float*)d_in[2];
    const float* wr  = (const float*)d_in[3];
    const float* br  = (const float*)d_in[4];
    const float* wz  = (const float*)d_in[5];
    const float* bz  = (const float*)d_in[6];
    const int*   seg = (const int*)d_in[7];

    int N = in_sizes[7];     // 2097152 tokens
    int G = out_size;        // 8192 segments

    int nblocks = (G + WPB - 1) / WPB;   // one wave per segment
    strength_seg_kernel<<<nblocks, BLOCK, 0, stream>>>(
        x, W1, b1, wr, br, wz, bz, seg, N, G, (float*)d_out);
}

// Round 3
// 55.121 us; speedup vs baseline: 3.0042x; 3.0042x over previous
//
#include <hip/hip_runtime.h>

#define SCALE_F 173.71779276130078f   // 400 / ln(10)
#define BLOCK 256
#define TPT 8                         // consecutive tokens per thread
#define NBINS 64

__global__ void zero_ws_kernel(float* __restrict__ ws, int n) {
    int i = blockIdx.x * 256 + threadIdx.x;
    if (i < n) ws[i] = 0.0f;
}

__global__ __launch_bounds__(BLOCK) void strength_main_kernel(
    const float* __restrict__ x,    // [N][6]
    const float* __restrict__ W1,   // [6][32]
    const float* __restrict__ b1,   // [32]
    const float* __restrict__ wr,   // [32]
    const float* __restrict__ brp,  // scalar
    const float* __restrict__ wz,   // [32]
    const float* __restrict__ bzp,  // scalar
    const int*   __restrict__ seg,  // [N] sorted
    int N, int G,
    float* __restrict__ num,        // [G]
    float* __restrict__ den)        // [G]
{
    __shared__ float4 WB[6][8];                 // W1 rows as 8 float4 col-blocks
    __shared__ float4 B1s[8], WRs[8], WZs[8];
    __shared__ float  binE[NBINS], binR[NBINS];
    __shared__ int    baseSeg_s;

    const int tid = threadIdx.x;

    // stage weights (flat float4 f -> row f/8, col-block f%8 : matches WB[6][8])
    if (tid < 48)                 ((float4*)WB)[tid]  = ((const float4*)W1)[tid];
    else if (tid < 56)            B1s[tid - 48]       = ((const float4*)b1)[tid - 48];
    else if (tid < 64)            WRs[tid - 56]       = ((const float4*)wr)[tid - 56];
    else if (tid < 72)            WZs[tid - 64]       = ((const float4*)wz)[tid - 64];
    if (tid < NBINS) { binE[tid] = 0.0f; binR[tid] = 0.0f; }
    if (tid == 0) {
        long t = (long)blockIdx.x * (BLOCK * TPT);
        baseSeg_s = seg[t < N ? t : (N - 1)];
    }
    __syncthreads();
    const int baseSeg = baseSeg_s;

    const long t0   = (long)blockIdx.x * (BLOCK * TPT) + (long)tid * TPT;
    const int  kmax = (t0 >= N) ? 0 : (int)((N - t0 < TPT) ? (N - t0) : TPT);

    // ---- load 8 tokens' features (48 floats = 12 float4) + 8 seg ids ----
    float a[TPT * 6];
    int   sg[TPT];
    if (kmax == TPT) {
        const float4* xp = (const float4*)(x + (size_t)t0 * 6);   // 192B-aligned
        #pragma unroll
        for (int i = 0; i < 12; ++i) {
            float4 v = xp[i];
            a[4 * i + 0] = v.x; a[4 * i + 1] = v.y;
            a[4 * i + 2] = v.z; a[4 * i + 3] = v.w;
        }
        const int4* sp = (const int4*)(seg + t0);
        int4 s0 = sp[0], s1 = sp[1];
        sg[0] = s0.x; sg[1] = s0.y; sg[2] = s0.z; sg[3] = s0.w;
        sg[4] = s1.x; sg[5] = s1.y; sg[6] = s1.z; sg[7] = s1.w;
    } else {
        #pragma unroll
        for (int k = 0; k < TPT; ++k) {
            if (k < kmax) {
                const float* xp = x + (size_t)(t0 + k) * 6;
                #pragma unroll
                for (int i = 0; i < 6; ++i) a[k * 6 + i] = xp[i];
                sg[k] = seg[t0 + k];
            } else {
                #pragma unroll
                for (int i = 0; i < 6; ++i) a[k * 6 + i] = 0.0f;
                sg[k] = -1;
            }
        }
    }

    const float brv = *brp;
    const float bzv = *bzp;

    float r[TPT], z[TPT];
    #pragma unroll
    for (int k = 0; k < TPT; ++k) { r[k] = brv; z[k] = bzv; }

    // ---- MLP: h_j = relu(x.W1[:,j]+b1_j); r += h*wr_j; z += h*wz_j ----
    #pragma unroll
    for (int jb = 0; jb < 8; ++jb) {
        const float4 w0 = WB[0][jb], w1 = WB[1][jb], w2 = WB[2][jb];
        const float4 w3 = WB[3][jb], w4 = WB[4][jb], w5 = WB[5][jb];
        const float4 bb = B1s[jb], rr = WRs[jb], zz = WZs[jb];
        #pragma unroll
        for (int k = 0; k < TPT; ++k) {
            const float* xk = &a[k * 6];
            {   float h = fmaf(xk[0], w0.x, fmaf(xk[1], w1.x, fmaf(xk[2], w2.x,
                          fmaf(xk[3], w3.x, fmaf(xk[4], w4.x, fmaf(xk[5], w5.x, bb.x))))));
                h = fmaxf(h, 0.0f); r[k] = fmaf(h, rr.x, r[k]); z[k] = fmaf(h, zz.x, z[k]); }
            {   float h = fmaf(xk[0], w0.y, fmaf(xk[1], w1.y, fmaf(xk[2], w2.y,
                          fmaf(xk[3], w3.y, fmaf(xk[4], w4.y, fmaf(xk[5], w5.y, bb.y))))));
                h = fmaxf(h, 0.0f); r[k] = fmaf(h, rr.y, r[k]); z[k] = fmaf(h, zz.y, z[k]); }
            {   float h = fmaf(xk[0], w0.z, fmaf(xk[1], w1.z, fmaf(xk[2], w2.z,
                          fmaf(xk[3], w3.z, fmaf(xk[4], w4.z, fmaf(xk[5], w5.z, bb.z))))));
                h = fmaxf(h, 0.0f); r[k] = fmaf(h, rr.z, r[k]); z[k] = fmaf(h, zz.z, z[k]); }
            {   float h = fmaf(xk[0], w0.w, fmaf(xk[1], w1.w, fmaf(xk[2], w2.w,
                          fmaf(xk[3], w3.w, fmaf(xk[4], w4.w, fmaf(xk[5], w5.w, bb.w))))));
                h = fmaxf(h, 0.0f); r[k] = fmaf(h, rr.w, r[k]); z[k] = fmaf(h, zz.w, z[k]); }
        }
    }

    // ---- serial run accumulation over 8 consecutive tokens ----
    {
        int   cur = (kmax > 0) ? sg[0] : -1;
        float ce = 0.0f, cer = 0.0f;
        #pragma unroll
        for (int k = 0; k < TPT; ++k) {
            if (k < kmax) {
                float e  = __expf(z[k]);       // no max-shift: ratio invariant
                float er = e * r[k];
                if (sg[k] != cur) {
                    int b = cur - baseSeg;
                    if ((unsigned)b < NBINS) { atomicAdd(&binE[b], ce); atomicAdd(&binR[b], cer); }
                    else                     { atomicAdd(&den[cur], ce); atomicAdd(&num[cur], cer); }
                    cur = sg[k]; ce = 0.0f; cer = 0.0f;
                }
                ce += e; cer += er;
            }
        }
        if (kmax > 0) {
            int b = cur - baseSeg;
            if ((unsigned)b < NBINS) { atomicAdd(&binE[b], ce); atomicAdd(&binR[b], cer); }
            else                     { atomicAdd(&den[cur], ce); atomicAdd(&num[cur], cer); }
        }
    }

    __syncthreads();
    if (tid < NBINS) {
        float e = binE[tid];
        if (e != 0.0f) {
            int s = baseSeg + tid;
            atomicAdd(&den[s], e);
            atomicAdd(&num[s], binR[tid]);
        }
    }
}

__global__ void finalize_kernel(const float* __restrict__ num,
                                const float* __restrict__ den,
                                float* __restrict__ out, int G) {
    int g = blockIdx.x * 256 + threadIdx.x;
    if (g < G) {
        float d = den[g];
        out[g] = (d > 0.0f) ? (SCALE_F * num[g] / d) : 0.0f;
    }
}

extern "C" void kernel_launch(void* const* d_in, const int* in_sizes, int n_in,
                              void* d_out, int out_size, void* d_ws, size_t ws_size,
                              hipStream_t stream) {
    const float* x   = (const float*)d_in[0];
    const float* W1  = (const float*)d_in[1];
    const float* b1  = (const float*)d_in[2];
    const float* wr  = (const float*)d_in[3];
    const float* br  = (const float*)d_in[4];
    const float* wz  = (const float*)d_in[5];
    const float* bz  = (const float*)d_in[6];
    const int*   seg = (const int*)d_in[7];

    int N = in_sizes[7];     // 2097152
    int G = out_size;        // 8192

    float* num = (float*)d_ws;
    float* den = num + G;
    float* out = (float*)d_out;

    int zn = 2 * G;
    zero_ws_kernel<<<(zn + 255) / 256, 256, 0, stream>>>(num, zn);

    long tokens_per_block = (long)BLOCK * TPT;   // 2048
    int  nblocks = (int)(((long)N + tokens_per_block - 1) / tokens_per_block);
    strength_main_kernel<<<nblocks, BLOCK, 0, stream>>>(
        x, W1, b1, wr, br, wz, bz, seg, N, G, num, den);

    finalize_kernel<<<(G + 255) / 256, 256, 0, stream>>>(num, den, out, G);
}

// Round 4
// 34.697 us; speedup vs baseline: 4.7726x; 1.5886x over previous
//
#include <hip/hip_runtime.h>

#define SCALE_F 173.71779276130078f   // 400 / ln(10)
#define BLOCK 256
#define TPT 8                         // consecutive tokens per thread

__global__ void zero_ws_kernel(float* __restrict__ ws, int n) {
    int i = blockIdx.x * 256 + threadIdx.x;
    if (i < n) ws[i] = 0.0f;
}

__global__ __launch_bounds__(BLOCK, 4) void strength_main_kernel(
    const float* __restrict__ x,    // [N][6]
    const float* __restrict__ W1,   // [6][32]
    const float* __restrict__ b1,   // [32]
    const float* __restrict__ wr,   // [32]
    const float* __restrict__ brp,  // scalar
    const float* __restrict__ wz,   // [32]
    const float* __restrict__ bzp,  // scalar
    const int*   __restrict__ seg,  // [N] sorted
    int N,
    float* __restrict__ num,        // [G]
    float* __restrict__ den)        // [G]
{
    __shared__ float4 WB[6][8];                 // W1 as [row][colblock] float4
    __shared__ float4 B1s[8], WRs[8], WZs[8];

    const int tid  = threadIdx.x;
    const int lane = tid & 63;

    if (tid < 48)       ((float4*)WB)[tid] = ((const float4*)W1)[tid];
    else if (tid < 56)  B1s[tid - 48] = ((const float4*)b1)[tid - 48];
    else if (tid < 64)  WRs[tid - 56] = ((const float4*)wr)[tid - 56];
    else if (tid < 72)  WZs[tid - 64] = ((const float4*)wz)[tid - 64];
    __syncthreads();

    const long t0   = (long)blockIdx.x * (BLOCK * TPT) + (long)tid * TPT;
    const int  kmax = (t0 >= N) ? 0 : (int)((N - t0 < TPT) ? (N - t0) : TPT);

    // ---- load 8 consecutive tokens (12 float4) + 8 seg ids (2 int4) ----
    float a[TPT * 6];
    int   sg[TPT];
    if (kmax == TPT) {
        const float4* xp = (const float4*)(x + (size_t)t0 * 6);   // 96B-aligned
        #pragma unroll
        for (int i = 0; i < 12; ++i) {
            float4 v = xp[i];
            a[4 * i + 0] = v.x; a[4 * i + 1] = v.y;
            a[4 * i + 2] = v.z; a[4 * i + 3] = v.w;
        }
        const int4* sp = (const int4*)(seg + t0);
        int4 s0v = sp[0], s1v = sp[1];
        sg[0] = s0v.x; sg[1] = s0v.y; sg[2] = s0v.z; sg[3] = s0v.w;
        sg[4] = s1v.x; sg[5] = s1v.y; sg[6] = s1v.z; sg[7] = s1v.w;
    } else {
        #pragma unroll
        for (int k = 0; k < TPT; ++k) {
            if (k < kmax) {
                const float* xp = x + (size_t)(t0 + k) * 6;
                #pragma unroll
                for (int i = 0; i < 6; ++i) a[k * 6 + i] = xp[i];
                sg[k] = seg[t0 + k];
            } else {
                #pragma unroll
                for (int i = 0; i < 6; ++i) a[k * 6 + i] = 0.0f;
                sg[k] = -1;
            }
        }
    }

    const float brv = *brp;
    const float bzv = *bzp;

    float r[TPT], z[TPT];
    #pragma unroll
    for (int k = 0; k < TPT; ++k) { r[k] = brv; z[k] = bzv; }

    // ---- MLP: one 4-column weight block live at a time (VGPR control) ----
    #pragma unroll 1
    for (int jb = 0; jb < 8; ++jb) {
        const float4 w0 = WB[0][jb], w1 = WB[1][jb], w2 = WB[2][jb];
        const float4 w3 = WB[3][jb], w4 = WB[4][jb], w5 = WB[5][jb];
        const float4 bb = B1s[jb], rr = WRs[jb], zz = WZs[jb];
        #pragma unroll
        for (int k = 0; k < TPT; ++k) {
            const float xk0 = a[k*6+0], xk1 = a[k*6+1], xk2 = a[k*6+2];
            const float xk3 = a[k*6+3], xk4 = a[k*6+4], xk5 = a[k*6+5];
            {   float h = fmaf(xk0, w0.x, fmaf(xk1, w1.x, fmaf(xk2, w2.x,
                          fmaf(xk3, w3.x, fmaf(xk4, w4.x, fmaf(xk5, w5.x, bb.x))))));
                h = fmaxf(h, 0.0f); r[k] = fmaf(h, rr.x, r[k]); z[k] = fmaf(h, zz.x, z[k]); }
            {   float h = fmaf(xk0, w0.y, fmaf(xk1, w1.y, fmaf(xk2, w2.y,
                          fmaf(xk3, w3.y, fmaf(xk4, w4.y, fmaf(xk5, w5.y, bb.y))))));
                h = fmaxf(h, 0.0f); r[k] = fmaf(h, rr.y, r[k]); z[k] = fmaf(h, zz.y, z[k]); }
            {   float h = fmaf(xk0, w0.z, fmaf(xk1, w1.z, fmaf(xk2, w2.z,
                          fmaf(xk3, w3.z, fmaf(xk4, w4.z, fmaf(xk5, w5.z, bb.z))))));
                h = fmaxf(h, 0.0f); r[k] = fmaf(h, rr.z, r[k]); z[k] = fmaf(h, zz.z, z[k]); }
            {   float h = fmaf(xk0, w0.w, fmaf(xk1, w1.w, fmaf(xk2, w2.w,
                          fmaf(xk3, w3.w, fmaf(xk4, w4.w, fmaf(xk5, w5.w, bb.w))))));
                h = fmaxf(h, 0.0f); r[k] = fmaf(h, rr.w, r[k]); z[k] = fmaf(h, zz.w, z[k]); }
        }
    }

    // ---- per-thread serial run accumulation; rare interior boundaries
    //      flush straight to global (commutative adds -> correct) ----
    int   key = (kmax > 0) ? sg[0] : -1;
    float E = 0.0f, ER = 0.0f;
    #pragma unroll
    for (int k = 0; k < TPT; ++k) {
        if (k < kmax) {
            float e = __expf(z[k]);        // no max-shift: ratio invariant
            if (sg[k] != key) {            // ~3% of threads
                atomicAdd(&den[key], E);
                atomicAdd(&num[key], ER);
                key = sg[k]; E = 0.0f; ER = 0.0f;
            }
            E += e; ER = fmaf(e, r[k], ER);
        }
    }

    // ---- one segmented inclusive scan per wave over lane tails ----
    #pragma unroll
    for (int d = 1; d < 64; d <<= 1) {
        int   k2 = __shfl_up(key, d);
        float E2 = __shfl_up(E,   d);
        float R2 = __shfl_up(ER,  d);
        if (lane >= d && k2 == key) { E += E2; ER += R2; }
    }
    int knext = __shfl_down(key, 1);
    bool last = (lane == 63) || (knext != key);
    if (last && key >= 0) {
        atomicAdd(&den[key], E);
        atomicAdd(&num[key], ER);
    }
}

__global__ void finalize_kernel(const float* __restrict__ num,
                                const float* __restrict__ den,
                                float* __restrict__ out, int G) {
    int g = blockIdx.x * 256 + threadIdx.x;
    if (g < G) {
        float d = den[g];
        out[g] = (d > 0.0f) ? (SCALE_F * num[g] / d) : 0.0f;
    }
}

extern "C" void kernel_launch(void* const* d_in, const int* in_sizes, int n_in,
                              void* d_out, int out_size, void* d_ws, size_t ws_size,
                              hipStream_t stream) {
    const float* x   = (const float*)d_in[0];
    const float* W1  = (const float*)d_in[1];
    const float* b1  = (const float*)d_in[2];
    const float* wr  = (const float*)d_in[3];
    const float* br  = (const float*)d_in[4];
    const float* wz  = (const float*)d_in[5];
    const float* bz  = (const float*)d_in[6];
    const int*   seg = (const int*)d_in[7];

    int N = in_sizes[7];     // 2097152
    int G = out_size;        // 8192

    float* num = (float*)d_ws;
    float* den = num + G;
    float* out = (float*)d_out;

    int zn = 2 * G;
    zero_ws_kernel<<<(zn + 255) / 256, 256, 0, stream>>>(num, zn);

    long tokens_per_block = (long)BLOCK * TPT;   // 2048
    int  nblocks = (int)(((long)N + tokens_per_block - 1) / tokens_per_block);
    strength_main_kernel<<<nblocks, BLOCK, 0, stream>>>(
        x, W1, b1, wr, br, wz, bz, seg, N, num, den);

    finalize_kernel<<<(G + 255) / 256, 256, 0, stream>>>(num, den, out, G);
}

// Round 5
// 30.290 us; speedup vs baseline: 5.4670x; 1.1455x over previous
//
#include <hip/hip_runtime.h>

#define SCALE_F 173.71779276130078f   // 400 / ln(10)
#define BLOCK 256
#define TPT 4                         // consecutive tokens per thread

__global__ void zero_ws_kernel(float* __restrict__ ws, int n) {
    int i = blockIdx.x * 256 + threadIdx.x;
    if (i < n) ws[i] = 0.0f;
}

__global__ __launch_bounds__(BLOCK, 8) void strength_main_kernel(
    const float* __restrict__ x,    // [N][6]
    const float* __restrict__ W1,   // [6][32]
    const float* __restrict__ b1,   // [32]
    const float* __restrict__ wr,   // [32]
    const float* __restrict__ brp,  // scalar
    const float* __restrict__ wz,   // [32]
    const float* __restrict__ bzp,  // scalar
    const int*   __restrict__ seg,  // [N] sorted
    int N,
    float* __restrict__ num,        // [G]
    float* __restrict__ den)        // [G]
{
    __shared__ float Ws[192];                   // W1 row-major [6][32]
    __shared__ float B1s[32], WRs[32], WZs[32];

    const int tid  = threadIdx.x;
    const int lane = tid & 63;

    if (tid < 48)       ((float4*)Ws)[tid]       = ((const float4*)W1)[tid];
    else if (tid < 56)  ((float4*)B1s)[tid - 48] = ((const float4*)b1)[tid - 48];
    else if (tid < 64)  ((float4*)WRs)[tid - 56] = ((const float4*)wr)[tid - 56];
    else if (tid < 72)  ((float4*)WZs)[tid - 64] = ((const float4*)wz)[tid - 64];
    __syncthreads();

    const int t0   = blockIdx.x * (BLOCK * TPT) + tid * TPT;
    const int kmax = (t0 >= N) ? 0 : ((N - t0 < TPT) ? (N - t0) : TPT);

    // ---- load 4 consecutive tokens (6 float4 = 96B) + 4 seg ids ----
    float a[TPT * 6];
    int   sg[TPT];
    if (kmax == TPT) {
        const float4* xp = (const float4*)(x + (size_t)t0 * 6);
        #pragma unroll
        for (int i = 0; i < 6; ++i) {
            float4 v = xp[i];
            a[4 * i + 0] = v.x; a[4 * i + 1] = v.y;
            a[4 * i + 2] = v.z; a[4 * i + 3] = v.w;
        }
        int4 s0v = *(const int4*)(seg + t0);
        sg[0] = s0v.x; sg[1] = s0v.y; sg[2] = s0v.z; sg[3] = s0v.w;
    } else {
        #pragma unroll
        for (int k = 0; k < TPT; ++k) {
            if (k < kmax) {
                const float* xp = x + (size_t)(t0 + k) * 6;
                #pragma unroll
                for (int i = 0; i < 6; ++i) a[k * 6 + i] = xp[i];
                sg[k] = seg[t0 + k];
            } else {
                #pragma unroll
                for (int i = 0; i < 6; ++i) a[k * 6 + i] = 0.0f;
                sg[k] = -1;
            }
        }
    }

    const float brv = *brp;
    const float bzv = *bzp;

    float r[TPT], z[TPT];
    #pragma unroll
    for (int k = 0; k < TPT; ++k) { r[k] = brv; z[k] = bzv; }

    // ---- MLP over 16 column-pairs; only 18 weight floats live at a time ----
    #pragma unroll 1
    for (int c = 0; c < 16; ++c) {
        const float2 w0 = *(const float2*)&Ws[0 * 32 + 2 * c];
        const float2 w1 = *(const float2*)&Ws[1 * 32 + 2 * c];
        const float2 w2 = *(const float2*)&Ws[2 * 32 + 2 * c];
        const float2 w3 = *(const float2*)&Ws[3 * 32 + 2 * c];
        const float2 w4 = *(const float2*)&Ws[4 * 32 + 2 * c];
        const float2 w5 = *(const float2*)&Ws[5 * 32 + 2 * c];
        const float2 bb = *(const float2*)&B1s[2 * c];
        const float2 rr = *(const float2*)&WRs[2 * c];
        const float2 zz = *(const float2*)&WZs[2 * c];
        #pragma unroll
        for (int k = 0; k < TPT; ++k) {
            const float a0 = a[k*6+0], a1 = a[k*6+1], a2 = a[k*6+2];
            const float a3 = a[k*6+3], a4 = a[k*6+4], a5 = a[k*6+5];
            // two columns, adjacent ops (SLP-packable into v_pk_fma_f32)
            float h0 = fmaf(a0, w0.x, fmaf(a1, w1.x, fmaf(a2, w2.x,
                       fmaf(a3, w3.x, fmaf(a4, w4.x, fmaf(a5, w5.x, bb.x))))));
            float h1 = fmaf(a0, w0.y, fmaf(a1, w1.y, fmaf(a2, w2.y,
                       fmaf(a3, w3.y, fmaf(a4, w4.y, fmaf(a5, w5.y, bb.y))))));
            h0 = fmaxf(h0, 0.0f);
            h1 = fmaxf(h1, 0.0f);
            r[k] = fmaf(h0, rr.x, fmaf(h1, rr.y, r[k]));
            z[k] = fmaf(h0, zz.x, fmaf(h1, zz.y, z[k]));
        }
    }

    // ---- per-thread serial run accumulation; interior boundaries flush
    //      straight to global (adds commute -> correct) ----
    int   key = (kmax > 0) ? sg[0] : -1;
    float E = 0.0f, ER = 0.0f;
    #pragma unroll
    for (int k = 0; k < TPT; ++k) {
        if (k < kmax) {
            float e = __expf(z[k]);        // no max-shift: ratio invariant
            if (sg[k] != key) {            // rare (~1.5% of threads)
                atomicAdd(&den[key], E);
                atomicAdd(&num[key], ER);
                key = sg[k]; E = 0.0f; ER = 0.0f;
            }
            E += e; ER = fmaf(e, r[k], ER);
        }
    }

    // ---- one segmented inclusive scan per wave over lane tails ----
    #pragma unroll
    for (int d = 1; d < 64; d <<= 1) {
        int   k2 = __shfl_up(key, d);
        float E2 = __shfl_up(E,   d);
        float R2 = __shfl_up(ER,  d);
        if (lane >= d && k2 == key) { E += E2; ER += R2; }
    }
    int knext = __shfl_down(key, 1);
    bool last = (lane == 63) || (knext != key);
    if (last && key >= 0) {
        atomicAdd(&den[key], E);
        atomicAdd(&num[key], ER);
    }
}

__global__ void finalize_kernel(const float* __restrict__ num,
                                const float* __restrict__ den,
                                float* __restrict__ out, int G) {
    int g = blockIdx.x * 256 + threadIdx.x;
    if (g < G) {
        float d = den[g];
        out[g] = (d > 0.0f) ? (SCALE_F * num[g] / d) : 0.0f;
    }
}

extern "C" void kernel_launch(void* const* d_in, const int* in_sizes, int n_in,
                              void* d_out, int out_size, void* d_ws, size_t ws_size,
                              hipStream_t stream) {
    const float* x   = (const float*)d_in[0];
    const float* W1  = (const float*)d_in[1];
    const float* b1  = (const float*)d_in[2];
    const float* wr  = (const float*)d_in[3];
    const float* br  = (const float*)d_in[4];
    const float* wz  = (const float*)d_in[5];
    const float* bz  = (const float*)d_in[6];
    const int*   seg = (const int*)d_in[7];

    int N = in_sizes[7];     // 2097152
    int G = out_size;        // 8192

    float* num = (float*)d_ws;
    float* den = num + G;
    float* out = (float*)d_out;

    int zn = 2 * G;
    zero_ws_kernel<<<(zn + 255) / 256, 256, 0, stream>>>(num, zn);

    long tokens_per_block = (long)BLOCK * TPT;   // 1024
    int  nblocks = (int)(((long)N + tokens_per_block - 1) / tokens_per_block);
    strength_main_kernel<<<nblocks, BLOCK, 0, stream>>>(
        x, W1, b1, wr, br, wz, bz, seg, N, num, den);

    finalize_kernel<<<(G + 255) / 256, 256, 0, stream>>>(num, den, out, G);
}